// Round 8
// baseline (370.481 us; speedup 1.0000x reference)
//
#include <hip/hip_runtime.h>
#include <stdint.h>

#define FEA 60
#define HID 256
#define MACH 22
#define PERM 316             // HID + FEA (reference layout)
#define PERM2 320            // padded per-machine stride (mult of 8)
#define FLATP2 (MACH * PERM2)   // 7040
#define NEG 0.01f
#define BCAP 64              // adjacency bucket capacity
#define S0 16                // mlp0 K-slices (Kc=448)
#define KC0 448

typedef __bf16 bf16x8 __attribute__((ext_vector_type(8)));
typedef float f32x4 __attribute__((ext_vector_type(4)));

__device__ __forceinline__ float bf2f(uint16_t u) {
    return __uint_as_float(((uint32_t)u) << 16);
}
__device__ __forceinline__ uint16_t f2bf(float f) {   // RNE
    uint32_t x = __float_as_uint(f);
    return (uint16_t)((x + 0x7fffu + ((x >> 16) & 1u)) >> 16);
}

// ---------------- detect dtypes + zero count + zero z0acc ----------------
__global__ void k_detect_init(const uint32_t* ew_w, const uint32_t* ei_w, int* flags,
                              int* count, float* z0acc, int n) {
    int i = blockIdx.x * blockDim.x + threadIdx.x;
    if (i < n) count[i] = 0;
    z0acc[i] = 0.f;
    if (blockIdx.x == 0) {
        __shared__ int c15, onz;
        if (threadIdx.x == 0) { c15 = 0; onz = 0; }
        __syncthreads();
        int a = 0, b = 0;
        for (int k = threadIdx.x; k < 1024; k += 256) {
            if (ew_w[k] & 0x8000u) a++;
            if (ei_w[2 * k + 1] != 0u) b++;
        }
        atomicAdd(&c15, a); atomicAdd(&onz, b);
        __syncthreads();
        if (threadIdx.x == 0) {
            flags[0] = (c15 <= 100) ? 1 : 0;
            flags[1] = (onz < 8) ? 1 : 0;
        }
    }
}

// ---------------- mega prep: cvt + weight transposes + edge scatter ----------------
struct PrepAll {
    const void* xsrc; uint16_t* x64;
    const void* src8[8]; float* dst8[8]; long prefix[9]; int cnt8;
    const void* wf0; uint16_t* wf0t;
    const void* src3[3]; uint16_t* dst3[3];
    const void* w1; uint16_t* w1t;
    const void* ei; const void* ew; int* count; uint2* adj; int E;
    int n;
};

#define NB_CVT 1024
#define NB_TR  492

__global__ __launch_bounds__(256) void k_prep_all(PrepAll a, const int* flags) {
    int isbf = flags[0];
    int b = blockIdx.x;
    int t = threadIdx.x;
    if (b < NB_CVT) {
        long nx = (long)a.n * 64;
        long total = nx + a.prefix[a.cnt8];
        for (long i = (long)b * 256 + t; i < total; i += (long)NB_CVT * 256) {
            if (i < nx) {
                int col = (int)(i & 63);
                long row = i >> 6;
                uint16_t v = 0;
                if (col < FEA) {
                    long s = row * FEA + col;
                    v = isbf ? ((const uint16_t*)a.xsrc)[s] : f2bf(((const float*)a.xsrc)[s]);
                }
                a.x64[i] = v;
            } else {
                long ii = i - nx;
                int tt = 0;
                while (ii >= a.prefix[tt + 1]) tt++;
                long j = ii - a.prefix[tt];
                a.dst8[tt][j] = isbf ? bf2f(((const uint16_t*)a.src8[tt])[j])
                                     : ((const float*)a.src8[tt])[j];
            }
        }
    } else if (b < NB_CVT + NB_TR) {
        __shared__ uint16_t s[64][65];
        int bb = b - NB_CVT;
        if (bb < 440) {
            int g0 = (bb >> 2) * 64, n0 = (bb & 3) * 64;
#pragma unroll
            for (int i = 0; i < 16; i++) {
                int idx = t + i * 256;
                int gg = idx >> 6, nn = idx & 63;
                int gk = g0 + gg;
                int m = gk / PERM2;
                int k2 = gk - m * PERM2;
                uint16_t v = 0;
                if (k2 < PERM) {
                    long off = (long)(m * PERM + k2) * HID + n0 + nn;
                    v = isbf ? ((const uint16_t*)a.wf0)[off] : f2bf(((const float*)a.wf0)[off]);
                }
                s[gg][nn] = v;
            }
            __syncthreads();
#pragma unroll
            for (int i = 0; i < 16; i++) {
                int idx = t + i * 256;
                int nn = idx >> 6, gg = idx & 63;
                a.wf0t[(long)(n0 + nn) * FLATP2 + g0 + gg] = s[gg][nn];
            }
        } else if (bb < 488) {
            int idx0 = bb - 440;
            int z = idx0 >> 4, r = idx0 & 15;
            int k0 = (r >> 2) * 64, n0 = (r & 3) * 64;
            const void* W = a.src3[z];
            uint16_t* Wt = a.dst3[z];
#pragma unroll
            for (int i = 0; i < 16; i++) {
                int idx = t + i * 256;
                int kk = idx >> 6, nn = idx & 63;
                long off = (long)(k0 + kk) * HID + n0 + nn;
                s[kk][nn] = isbf ? ((const uint16_t*)W)[off] : f2bf(((const float*)W)[off]);
            }
            __syncthreads();
#pragma unroll
            for (int i = 0; i < 16; i++) {
                int idx = t + i * 256;
                int nn = idx >> 6, kk = idx & 63;
                Wt[(long)(n0 + nn) * HID + k0 + kk] = s[kk][nn];
            }
        } else {
            int n0 = (bb - 488) * 64;
#pragma unroll
            for (int i = 0; i < 16; i++) {
                int idx = t + i * 256;
                int kk = idx >> 6, nn = idx & 63;
                uint16_t v = 0;
                if (kk < FEA) {
                    long off = (long)kk * HID + n0 + nn;
                    v = isbf ? ((const uint16_t*)a.w1)[off] : f2bf(((const float*)a.w1)[off]);
                }
                s[kk][nn] = v;
            }
            __syncthreads();
#pragma unroll
            for (int i = 0; i < 16; i++) {
                int idx = t + i * 256;
                int nn = idx >> 6, kk = idx & 63;
                a.w1t[(long)(n0 + nn) * 64 + kk] = s[kk][nn];
            }
        }
    } else {
        // ---- bucket-CSR scatter, NT stores ----
        int e0 = ((b - NB_CVT - NB_TR) * 256 + t) * 2;
        int E = a.E;
        if (e0 >= E) return;
        int i64 = flags[1];
        int r0, r1 = -1, c0, c1 = -1;
        if (i64) {
            const long long* pr = (const long long*)a.ei + e0;
            const long long* pc = (const long long*)a.ei + E + e0;
            r0 = (int)pr[0]; c0 = (int)pc[0];
            if (e0 + 1 < E) { r1 = (int)pr[1]; c1 = (int)pc[1]; }
        } else {
            const int* pr = (const int*)a.ei + e0;
            const int* pc = (const int*)a.ei + E + e0;
            r0 = pr[0]; c0 = pc[0];
            if (e0 + 1 < E) { r1 = pr[1]; c1 = pc[1]; }
        }
        float w0, w1 = 0.f;
        if (isbf) {
            uint32_t ww = ((const uint32_t*)a.ew)[e0 >> 1];
            w0 = bf2f((uint16_t)(ww & 0xffff));
            w1 = bf2f((uint16_t)(ww >> 16));
        } else {
            float2 f = ((const float2*)a.ew)[e0 >> 1];
            w0 = f.x; w1 = f.y;
        }
        int p0 = atomicAdd(&a.count[c0], 1);
        unsigned long long v0 = (unsigned long long)(uint32_t)r0 |
                                ((unsigned long long)__float_as_uint(w0) << 32);
        __builtin_nontemporal_store(v0, (unsigned long long*)&a.adj[((long)c0 << 6) + p0]);
        if (c1 >= 0) {
            int p1 = atomicAdd(&a.count[c1], 1);
            unsigned long long v1 = (unsigned long long)(uint32_t)r1 |
                                    ((unsigned long long)__float_as_uint(w1) << 32);
            __builtin_nontemporal_store(v1, (unsigned long long*)&a.adj[((long)c1 << 6) + p1]);
        }
    }
}

// dinv = 1/sqrt(1 + row-sum of raw ew) over bucket
__global__ void k_rowsum(const int* count, const uint2* adj, float* dinv, int n) {
    int i = blockIdx.x * blockDim.x + threadIdx.x;
    if (i >= n) return;
    int cnt = count[i];
    const uint2* row = adj + ((long)i << 6);
    double d = 1.0;
    for (int p = 0; p < cnt; p++) d += (double)__uint_as_float(row[p].y);
    dinv[i] = (float)(1.0 / sqrt(d));
}

// ---------------- layer-1 pre-aggregation, column-split x2 (XCD parity) --------
// colgroup = blockIdx.x & 1 (32 of 64 cols); 16 lanes/node; 16 nodes/block
__global__ __launch_bounds__(256) void k_aggx(const uint16_t* __restrict__ x64,
                                              const float* __restrict__ dinv,
                                              const int* __restrict__ count,
                                              const uint2* __restrict__ adj,
                                              uint16_t* __restrict__ xa, int n) {
    __shared__ uint2 sadj[16][16];
    int cg = blockIdx.x & 1;
    int ng = blockIdx.x >> 1;
    int slot = threadIdx.x >> 4;
    int l = threadIdx.x & 15;
    int node = ng * 16 + slot;
    if (node >= n) return;
    const uint32_t* xu = (const uint32_t*)x64;
    int cbase = cg * 16;                    // uint col base (32 uints/row)
    float di = dinv[node];
    float c2 = di * di;
    uint32_t h = xu[(long)node * 32 + cbase + l];
    float a0 = c2 * bf2f((uint16_t)(h & 0xffff));
    float a1 = c2 * bf2f((uint16_t)(h >> 16));
    int cnt = count[node];
    const uint2* row = adj + ((long)node << 6);
    for (int base = 0; base < cnt; base += 16) {
        int m = cnt - base; if (m > 16) m = 16;
        if (l < m) {
            uint2 a = row[base + l];
            float w = __uint_as_float(a.y) * dinv[a.x] * di;
            uint2 p; p.x = a.x; p.y = __float_as_uint(w);
            sadj[slot][l] = p;
        }
        int t = 0;
        for (; t + 4 <= m; t += 4) {
            uint2 e0 = sadj[slot][t], e1 = sadj[slot][t + 1];
            uint2 e2 = sadj[slot][t + 2], e3 = sadj[slot][t + 3];
            uint32_t v0 = xu[(long)e0.x * 32 + cbase + l];
            uint32_t v1 = xu[(long)e1.x * 32 + cbase + l];
            uint32_t v2 = xu[(long)e2.x * 32 + cbase + l];
            uint32_t v3 = xu[(long)e3.x * 32 + cbase + l];
            float w0 = __uint_as_float(e0.y), w1 = __uint_as_float(e1.y);
            float w2 = __uint_as_float(e2.y), w3 = __uint_as_float(e3.y);
            a0 += w0 * bf2f((uint16_t)(v0 & 0xffff)); a1 += w0 * bf2f((uint16_t)(v0 >> 16));
            a0 += w1 * bf2f((uint16_t)(v1 & 0xffff)); a1 += w1 * bf2f((uint16_t)(v1 >> 16));
            a0 += w2 * bf2f((uint16_t)(v2 & 0xffff)); a1 += w2 * bf2f((uint16_t)(v2 >> 16));
            a0 += w3 * bf2f((uint16_t)(v3 & 0xffff)); a1 += w3 * bf2f((uint16_t)(v3 >> 16));
        }
        for (; t < m; t++) {
            uint2 e0 = sadj[slot][t];
            uint32_t v0 = xu[(long)e0.x * 32 + cbase + l];
            float w0 = __uint_as_float(e0.y);
            a0 += w0 * bf2f((uint16_t)(v0 & 0xffff));
            a1 += w0 * bf2f((uint16_t)(v0 >> 16));
        }
    }
    ((uint32_t*)xa)[(long)node * 32 + cbase + l] =
        (uint32_t)f2bf(a0) | ((uint32_t)f2bf(a1) << 16);
}

// ---------------- layer-2 aggregation, column-split x8 (XCD-affine) ----------
// colgroup = blockIdx.x & 7 (32 of 256 cols -> 2.88 MB slice fits 4 MB XCD L2)
__global__ __launch_bounds__(256) void k_aggb(const uint16_t* __restrict__ hw,
                                              const float* __restrict__ dinv,
                                              const int* __restrict__ count,
                                              const uint2* __restrict__ adj,
                                              const float* __restrict__ bias,
                                              uint16_t* __restrict__ out, int n) {
    __shared__ uint2 sadj[16][16];
    int cg = blockIdx.x & 7;
    int ng = blockIdx.x >> 3;
    int slot = threadIdx.x >> 4;
    int l = threadIdx.x & 15;
    int node = ng * 16 + slot;
    if (node >= n) return;
    const uint32_t* hwu = (const uint32_t*)hw;
    int cbase = cg * 16;                    // uint col base (128 uints/row)
    float di = dinv[node];
    float c2 = di * di;
    uint32_t h = hwu[(long)node * 128 + cbase + l];
    float a0 = c2 * bf2f((uint16_t)(h & 0xffff));
    float a1 = c2 * bf2f((uint16_t)(h >> 16));
    int cnt = count[node];
    const uint2* row = adj + ((long)node << 6);
    for (int base = 0; base < cnt; base += 16) {
        int m = cnt - base; if (m > 16) m = 16;
        if (l < m) {
            uint2 a = row[base + l];
            float w = __uint_as_float(a.y) * dinv[a.x] * di;
            uint2 p; p.x = a.x; p.y = __float_as_uint(w);
            sadj[slot][l] = p;
        }
        int t = 0;
        for (; t + 4 <= m; t += 4) {
            uint2 e0 = sadj[slot][t], e1 = sadj[slot][t + 1];
            uint2 e2 = sadj[slot][t + 2], e3 = sadj[slot][t + 3];
            uint32_t v0 = hwu[(long)e0.x * 128 + cbase + l];
            uint32_t v1 = hwu[(long)e1.x * 128 + cbase + l];
            uint32_t v2 = hwu[(long)e2.x * 128 + cbase + l];
            uint32_t v3 = hwu[(long)e3.x * 128 + cbase + l];
            float w0 = __uint_as_float(e0.y), w1 = __uint_as_float(e1.y);
            float w2 = __uint_as_float(e2.y), w3 = __uint_as_float(e3.y);
            a0 += w0 * bf2f((uint16_t)(v0 & 0xffff)); a1 += w0 * bf2f((uint16_t)(v0 >> 16));
            a0 += w1 * bf2f((uint16_t)(v1 & 0xffff)); a1 += w1 * bf2f((uint16_t)(v1 >> 16));
            a0 += w2 * bf2f((uint16_t)(v2 & 0xffff)); a1 += w2 * bf2f((uint16_t)(v2 >> 16));
            a0 += w3 * bf2f((uint16_t)(v3 & 0xffff)); a1 += w3 * bf2f((uint16_t)(v3 >> 16));
        }
        for (; t < m; t++) {
            uint2 e0 = sadj[slot][t];
            uint32_t v0 = hwu[(long)e0.x * 128 + cbase + l];
            float w0 = __uint_as_float(e0.y);
            a0 += w0 * bf2f((uint16_t)(v0 & 0xffff));
            a1 += w0 * bf2f((uint16_t)(v0 >> 16));
        }
    }
    float2 bv = ((const float2*)bias)[cbase + l];
    a0 += bv.x; a1 += bv.y;
    a0 = a0 > 0.f ? a0 : NEG * a0;
    a1 = a1 > 0.f ? a1 : NEG * a1;
    ((uint32_t*)out)[(long)node * 128 + cbase + l] =
        (uint32_t)f2bf(a0) | ((uint32_t)f2bf(a1) << 16);
}

// ---------------- bf16 MFMA GEMM (plain A) ----------------
__global__ __launch_bounds__(256) void k_mgemm(const uint16_t* __restrict__ A,
                                               const uint16_t* __restrict__ Bt,
                                               uint16_t* __restrict__ outb,
                                               const float* __restrict__ bias,
                                               int M, int K, int act) {
    __shared__ uint16_t As[128 * 40];
    __shared__ uint16_t Bs[128 * 40];
    int tid = threadIdx.x;
    int lane = tid & 63, wv = tid >> 6;
    int quad = lane >> 4, l15 = lane & 15;
    int row0 = blockIdx.y * 128, col0 = blockIdx.x * 128;
    int arow = (wv >> 1) * 64;
    int bcol = (wv & 1) * 64;

    f32x4 acc[4][4];
#pragma unroll
    for (int i = 0; i < 4; i++)
#pragma unroll
        for (int j = 0; j < 4; j++) acc[i][j] = (f32x4){0.f, 0.f, 0.f, 0.f};

    for (int kc = 0; kc < K; kc += 32) {
#pragma unroll
        for (int i = 0; i < 2; i++) {
            int idx = tid + i * 256;
            int r = idx >> 2, cq = idx & 3;
            uint4 va = *(const uint4*)(A + (long)(row0 + r) * K + kc + cq * 8);
            *(uint4*)(&As[r * 40 + cq * 8]) = va;
            uint4 vb = *(const uint4*)(Bt + (long)(col0 + r) * K + kc + cq * 8);
            *(uint4*)(&Bs[r * 40 + cq * 8]) = vb;
        }
        __syncthreads();
        bf16x8 af[4], bfr[4];
#pragma unroll
        for (int i = 0; i < 4; i++)
            af[i] = __builtin_bit_cast(bf16x8,
                *(const uint4*)(&As[(arow + i * 16 + l15) * 40 + quad * 8]));
#pragma unroll
        for (int j = 0; j < 4; j++)
            bfr[j] = __builtin_bit_cast(bf16x8,
                *(const uint4*)(&Bs[(bcol + j * 16 + l15) * 40 + quad * 8]));
#pragma unroll
        for (int i = 0; i < 4; i++)
#pragma unroll
            for (int j = 0; j < 4; j++)
                acc[i][j] = __builtin_amdgcn_mfma_f32_16x16x32_bf16(af[i], bfr[j], acc[i][j], 0, 0, 0);
        __syncthreads();
    }

#pragma unroll
    for (int i = 0; i < 4; i++)
#pragma unroll
        for (int j = 0; j < 4; j++) {
            int row = row0 + arow + i * 16 + quad * 4;
            int col = col0 + bcol + j * 16 + l15;
#pragma unroll
            for (int reg = 0; reg < 4; reg++) {
                float v = acc[i][j][reg];
                if (bias) v += bias[col];
                if (act) v = v > 0.f ? v : NEG * v;
                outb[(long)(row + reg) * HID + col] = f2bf(v);
            }
        }
}

// ---------------- bf16 MFMA GEMM, VIRTUAL flat A (mlp0), atomic epilogue ----------
__global__ __launch_bounds__(256) void k_mgemm_flat(const uint16_t* __restrict__ h2,
                                                    const uint16_t* __restrict__ x64,
                                                    const uint16_t* __restrict__ Bt,
                                                    float* __restrict__ z0acc,
                                                    int M) {
    __shared__ uint16_t As[128 * 40];
    __shared__ uint16_t Bs[128 * 40];
    int tid = threadIdx.x;
    int lane = tid & 63, wv = tid >> 6;
    int quad = lane >> 4, l15 = lane & 15;
    int row0 = blockIdx.y * 128, col0 = blockIdx.x * 128;
    int kbeg = blockIdx.z * KC0;
    int kend = kbeg + KC0; if (kend > FLATP2) kend = FLATP2;
    int arow = (wv >> 1) * 64;
    int bcol = (wv & 1) * 64;

    f32x4 acc[4][4];
#pragma unroll
    for (int i = 0; i < 4; i++)
#pragma unroll
        for (int j = 0; j < 4; j++) acc[i][j] = (f32x4){0.f, 0.f, 0.f, 0.f};

    for (int kc = kbeg; kc < kend; kc += 32) {
#pragma unroll
        for (int i = 0; i < 2; i++) {
            int idx = tid + i * 256;
            int r = idx >> 2, cq = idx & 3;
            int gk = kc + cq * 8;
            int m = gk / PERM2;
            int k2 = gk - m * PERM2;
            long node = (long)(row0 + r) * MACH + m;
            uint4 va = (k2 < HID)
                ? *(const uint4*)(h2 + node * HID + k2)
                : *(const uint4*)(x64 + node * 64 + (k2 - HID));
            *(uint4*)(&As[r * 40 + cq * 8]) = va;
            uint4 vb = *(const uint4*)(Bt + (long)(col0 + r) * FLATP2 + gk);
            *(uint4*)(&Bs[r * 40 + cq * 8]) = vb;
        }
        __syncthreads();
        bf16x8 af[4], bfr[4];
#pragma unroll
        for (int i = 0; i < 4; i++)
            af[i] = __builtin_bit_cast(bf16x8,
                *(const uint4*)(&As[(arow + i * 16 + l15) * 40 + quad * 8]));
#pragma unroll
        for (int j = 0; j < 4; j++)
            bfr[j] = __builtin_bit_cast(bf16x8,
                *(const uint4*)(&Bs[(bcol + j * 16 + l15) * 40 + quad * 8]));
#pragma unroll
        for (int i = 0; i < 4; i++)
#pragma unroll
            for (int j = 0; j < 4; j++)
                acc[i][j] = __builtin_amdgcn_mfma_f32_16x16x32_bf16(af[i], bfr[j], acc[i][j], 0, 0, 0);
        __syncthreads();
    }

#pragma unroll
    for (int i = 0; i < 4; i++)
#pragma unroll
        for (int j = 0; j < 4; j++) {
            int row = row0 + arow + i * 16 + quad * 4;
            int col = col0 + bcol + j * 16 + l15;
#pragma unroll
            for (int reg = 0; reg < 4; reg++)
                atomicAdd(&z0acc[(long)(row + reg) * HID + col], acc[i][j][reg]);
        }
}

// ---------------- fused tail: z0acc+bf0+lrelu -> mlp1 -> mlp2 -> out ------
__global__ __launch_bounds__(256) void k_tail(const float* __restrict__ z0acc,
                                              const float* __restrict__ bf0,
                                              const uint16_t* __restrict__ Wf1t,
                                              const float* __restrict__ bf1,
                                              const uint16_t* __restrict__ Wf2t,
                                              const float* __restrict__ bf2,
                                              const float* __restrict__ Wo,
                                              const float* __restrict__ bo,
                                              void* out, const int* flags) {
    __shared__ uint16_t z0s[16 * 256];
    __shared__ uint16_t z1s[16 * 256];
    __shared__ uint16_t z2s[16 * 256];
    int tid = threadIdx.x;
    int lane = tid & 63, wv = tid >> 6;
    int quad = lane >> 4, l15 = lane & 15;
    int rows0 = blockIdx.x * 16;
    int nw = wv * 64;

    for (int i = tid; i < 16 * 256; i += 256) {
        int rr = i >> 8, cc = i & 255;
        float v = z0acc[(long)(rows0 + rr) * HID + cc] + bf0[cc];
        v = v > 0.f ? v : NEG * v;
        z0s[i] = f2bf(v);
    }
    __syncthreads();

    {
        f32x4 acc[4];
#pragma unroll
        for (int j = 0; j < 4; j++) acc[j] = (f32x4){0.f, 0.f, 0.f, 0.f};
        for (int kc = 0; kc < HID; kc += 32) {
            bf16x8 a = __builtin_bit_cast(bf16x8,
                *(const uint4*)(&z0s[l15 * 256 + kc + quad * 8]));
#pragma unroll
            for (int j = 0; j < 4; j++) {
                bf16x8 b = __builtin_bit_cast(bf16x8,
                    *(const uint4*)(Wf1t + (long)(nw + j * 16 + l15) * HID + kc + quad * 8));
                acc[j] = __builtin_amdgcn_mfma_f32_16x16x32_bf16(a, b, acc[j], 0, 0, 0);
            }
        }
#pragma unroll
        for (int j = 0; j < 4; j++) {
            int col = nw + j * 16 + l15;
            float bj = bf1[col];
#pragma unroll
            for (int reg = 0; reg < 4; reg++) {
                float v = acc[j][reg] + bj;
                v = v > 0.f ? v : NEG * v;
                z1s[(quad * 4 + reg) * 256 + col] = f2bf(v);
            }
        }
    }
    __syncthreads();

    {
        f32x4 acc[4];
#pragma unroll
        for (int j = 0; j < 4; j++) acc[j] = (f32x4){0.f, 0.f, 0.f, 0.f};
        for (int kc = 0; kc < HID; kc += 32) {
            bf16x8 a = __builtin_bit_cast(bf16x8,
                *(const uint4*)(&z1s[l15 * 256 + kc + quad * 8]));
#pragma unroll
            for (int j = 0; j < 4; j++) {
                bf16x8 b = __builtin_bit_cast(bf16x8,
                    *(const uint4*)(Wf2t + (long)(nw + j * 16 + l15) * HID + kc + quad * 8));
                acc[j] = __builtin_amdgcn_mfma_f32_16x16x32_bf16(a, b, acc[j], 0, 0, 0);
            }
        }
#pragma unroll
        for (int j = 0; j < 4; j++) {
            int col = nw + j * 16 + l15;
            float bj = bf2[col];
#pragma unroll
            for (int reg = 0; reg < 4; reg++) {
                float v = acc[j][reg] + bj;
                v = v > 0.f ? v : NEG * v;
                z2s[(quad * 4 + reg) * 256 + col] = f2bf(v);
            }
        }
    }
    __syncthreads();

    if (tid < 64) {
        int r = tid >> 2, o = tid & 3;
        float acc = bo[o];
        for (int k = 0; k < HID; k++)
            acc += bf2f(z2s[r * 256 + k]) * Wo[k * 4 + o];
        long idx = (long)(rows0 + r) * 4 + o;
        if (flags[0]) ((uint16_t*)out)[idx] = f2bf(acc);
        else          ((float*)out)[idx] = acc;
    }
}

// ---------------- host ----------------
extern "C" void kernel_launch(void* const* d_in, const int* in_sizes, int n_in,
                              void* d_out, int out_size, void* d_ws, size_t ws_size,
                              hipStream_t stream) {
    const int N  = in_sizes[0] / FEA;   // 45056
    const int E  = in_sizes[2];         // 720896
    const int Bn = N / MACH;            // 2048

    char* ws = (char*)d_ws;
    size_t off = 0;
    auto alloc = [&](size_t bytes) -> char* {
        char* p = ws + off;
        off = (off + bytes + 255) & ~(size_t)255;
        return p;
    };

    int*      flags  = (int*)     alloc(64);
    uint16_t* x64    = (uint16_t*)alloc((size_t)N * 64 * 2);
    uint16_t* xa     = (uint16_t*)alloc((size_t)N * 64 * 2);
    uint16_t* W1t    = (uint16_t*)alloc((size_t)HID * 64 * 2);
    uint16_t* W2t    = (uint16_t*)alloc((size_t)HID * HID * 2);
    uint16_t* Wf0t   = (uint16_t*)alloc((size_t)HID * FLATP2 * 2);
    uint16_t* Wf1t   = (uint16_t*)alloc((size_t)HID * HID * 2);
    uint16_t* Wf2t   = (uint16_t*)alloc((size_t)HID * HID * 2);
    float*    b1     = (float*)   alloc(HID * 4);
    float*    b2     = (float*)   alloc(HID * 4);
    float*    bf0    = (float*)   alloc(HID * 4);
    float*    bf1    = (float*)   alloc(HID * 4);
    float*    bf2    = (float*)   alloc(HID * 4);
    float*    Wo     = (float*)   alloc((size_t)HID * 4 * 4);
    float*    bo     = (float*)   alloc(4 * 4);
    int*      count  = (int*)     alloc((size_t)N * 4);
    uint2*    adj    = (uint2*)   alloc((size_t)N * BCAP * 8);   // 23 MB buckets
    float*    dinv   = (float*)   alloc((size_t)N * 4);
    uint16_t* P      = (uint16_t*)alloc((size_t)N * HID * 2);    // h1 / h2
    uint16_t* Q      = (uint16_t*)alloc((size_t)N * HID * 2);    // hw
    float*    z0acc  = (float*)   alloc((size_t)Bn * HID * 4);   // 2 MB fp32 accumulator
    (void)ws_size; (void)n_in; (void)out_size;

    // 1. detect + zero count + zero z0acc
    k_detect_init<<<(Bn * HID) / 256, 256, 0, stream>>>(
        (const uint32_t*)d_in[2], (const uint32_t*)d_in[1], flags, count, z0acc, N);

    // 2. mega-prep: conversions + weight transposes + edge scatter
    PrepAll pa{};
    pa.xsrc = d_in[0]; pa.x64 = x64;
    const void* s8[7] = { d_in[4], d_in[6], d_in[8], d_in[10], d_in[12], d_in[13], d_in[14] };
    float* d8[7] = { b1, b2, bf0, bf1, bf2, Wo, bo };
    long n8[7] = { HID, HID, HID, HID, HID, (long)HID * 4, 4 };
    pa.cnt8 = 7;
    pa.prefix[0] = 0;
    for (int t = 0; t < 7; t++) { pa.src8[t] = s8[t]; pa.dst8[t] = d8[t]; pa.prefix[t + 1] = pa.prefix[t] + n8[t]; }
    pa.prefix[8] = pa.prefix[7];
    pa.wf0 = d_in[7]; pa.wf0t = Wf0t;
    pa.src3[0] = d_in[5];  pa.dst3[0] = W2t;
    pa.src3[1] = d_in[9];  pa.dst3[1] = Wf1t;
    pa.src3[2] = d_in[11]; pa.dst3[2] = Wf2t;
    pa.w1 = d_in[3]; pa.w1t = W1t;
    pa.ei = d_in[1]; pa.ew = d_in[2]; pa.count = count; pa.adj = adj; pa.E = E;
    pa.n = N;
    int nb_sc = (E / 2 + 255) / 256;
    k_prep_all<<<NB_CVT + NB_TR + nb_sc, 256, 0, stream>>>(pa, flags);

    // 3. dinv from buckets
    k_rowsum<<<(N + 255) / 256, 256, 0, stream>>>(count, adj, dinv, N);

    // 4. GCN layer 1: xa = agg(x64) [col-split x2] ; h1 = lrelu(xa @ W1t + b1)
    k_aggx<<<2 * ((N + 15) / 16), 256, 0, stream>>>(x64, dinv, count, adj, xa, N);
    k_mgemm<<<dim3(2, N / 128), 256, 0, stream>>>(xa, W1t, P, b1, N, 64, 1);

    // 5. GCN layer 2: hw = h1 @ W2t ; h2 = agg(hw) + b2, lrelu  [col-split x8]
    k_mgemm<<<dim3(2, N / 128), 256, 0, stream>>>(P, W2t, Q, nullptr, N, HID, 0);
    k_aggb<<<8 * ((N + 15) / 16), 256, 0, stream>>>(Q, dinv, count, adj, b2, P, N);

    // 6. mlp0: virtual-flat split-K (S=16, Kc=448), atomic accumulate into z0acc
    k_mgemm_flat<<<dim3(2, Bn / 128, S0), 256, 0, stream>>>(P, x64, Wf0t, z0acc, Bn);

    // 7. fused tail: bias/lrelu + mlp1 + mlp2 + out
    k_tail<<<Bn / 16, 256, 0, stream>>>(z0acc, bf0, Wf1t, bf1, Wf2t, bf2, Wo, bo,
                                        d_out, flags);
}

// Round 9
// 318.475 us; speedup vs baseline: 1.1633x; 1.1633x over previous
//
#include <hip/hip_runtime.h>
#include <stdint.h>

#define FEA 60
#define HID 256
#define MACH 22
#define PERM 316             // HID + FEA (reference layout)
#define PERM2 320            // padded per-machine stride (mult of 8)
#define FLATP2 (MACH * PERM2)   // 7040
#define NEG 0.01f
#define BCAP 64              // adjacency bucket capacity
#define S0 16                // mlp0 K-slices (Kc=448)
#define KC0 448

typedef __bf16 bf16x8 __attribute__((ext_vector_type(8)));
typedef float f32x4 __attribute__((ext_vector_type(4)));

__device__ __forceinline__ float bf2f(uint16_t u) {
    return __uint_as_float(((uint32_t)u) << 16);
}
__device__ __forceinline__ uint16_t f2bf(float f) {   // RNE
    uint32_t x = __float_as_uint(f);
    return (uint16_t)((x + 0x7fffu + ((x >> 16) & 1u)) >> 16);
}
__device__ __forceinline__ uint2 nt_load_u2(const uint2* p) {
    unsigned long long raw = __builtin_nontemporal_load((const unsigned long long*)p);
    uint2 v; v.x = (uint32_t)raw; v.y = (uint32_t)(raw >> 32);
    return v;
}

// ---------------- detect dtypes + zero count + zero z0acc ----------------
__global__ void k_detect_init(const uint32_t* ew_w, const uint32_t* ei_w, int* flags,
                              int* count, float* z0acc, int n) {
    int i = blockIdx.x * blockDim.x + threadIdx.x;
    if (i < n) count[i] = 0;
    z0acc[i] = 0.f;
    if (blockIdx.x == 0) {
        __shared__ int c15, onz;
        if (threadIdx.x == 0) { c15 = 0; onz = 0; }
        __syncthreads();
        int a = 0, b = 0;
        for (int k = threadIdx.x; k < 1024; k += 256) {
            if (ew_w[k] & 0x8000u) a++;
            if (ei_w[2 * k + 1] != 0u) b++;
        }
        atomicAdd(&c15, a); atomicAdd(&onz, b);
        __syncthreads();
        if (threadIdx.x == 0) {
            flags[0] = (c15 <= 100) ? 1 : 0;
            flags[1] = (onz < 8) ? 1 : 0;
        }
    }
}

// ---------------- mega prep: cvt + weight transposes + edge scatter ----------------
struct PrepAll {
    const void* xsrc; uint16_t* x64;
    const void* src8[8]; float* dst8[8]; long prefix[9]; int cnt8;
    const void* wf0; uint16_t* wf0t;
    const void* src3[3]; uint16_t* dst3[3];
    const void* w1; uint16_t* w1t;
    const void* ei; const void* ew; int* count; uint2* adj; int E;
    int n;
};

#define NB_CVT 1024
#define NB_TR  492

__global__ __launch_bounds__(256) void k_prep_all(PrepAll a, const int* flags) {
    int isbf = flags[0];
    int b = blockIdx.x;
    int t = threadIdx.x;
    if (b < NB_CVT) {
        long nx = (long)a.n * 64;
        long total = nx + a.prefix[a.cnt8];
        for (long i = (long)b * 256 + t; i < total; i += (long)NB_CVT * 256) {
            if (i < nx) {
                int col = (int)(i & 63);
                long row = i >> 6;
                uint16_t v = 0;
                if (col < FEA) {
                    long s = row * FEA + col;
                    v = isbf ? ((const uint16_t*)a.xsrc)[s] : f2bf(((const float*)a.xsrc)[s]);
                }
                a.x64[i] = v;
            } else {
                long ii = i - nx;
                int tt = 0;
                while (ii >= a.prefix[tt + 1]) tt++;
                long j = ii - a.prefix[tt];
                a.dst8[tt][j] = isbf ? bf2f(((const uint16_t*)a.src8[tt])[j])
                                     : ((const float*)a.src8[tt])[j];
            }
        }
    } else if (b < NB_CVT + NB_TR) {
        __shared__ uint16_t s[64][65];
        int bb = b - NB_CVT;
        if (bb < 440) {
            int g0 = (bb >> 2) * 64, n0 = (bb & 3) * 64;
#pragma unroll
            for (int i = 0; i < 16; i++) {
                int idx = t + i * 256;
                int gg = idx >> 6, nn = idx & 63;
                int gk = g0 + gg;
                int m = gk / PERM2;
                int k2 = gk - m * PERM2;
                uint16_t v = 0;
                if (k2 < PERM) {
                    long off = (long)(m * PERM + k2) * HID + n0 + nn;
                    v = isbf ? ((const uint16_t*)a.wf0)[off] : f2bf(((const float*)a.wf0)[off]);
                }
                s[gg][nn] = v;
            }
            __syncthreads();
#pragma unroll
            for (int i = 0; i < 16; i++) {
                int idx = t + i * 256;
                int nn = idx >> 6, gg = idx & 63;
                a.wf0t[(long)(n0 + nn) * FLATP2 + g0 + gg] = s[gg][nn];
            }
        } else if (bb < 488) {
            int idx0 = bb - 440;
            int z = idx0 >> 4, r = idx0 & 15;
            int k0 = (r >> 2) * 64, n0 = (r & 3) * 64;
            const void* W = a.src3[z];
            uint16_t* Wt = a.dst3[z];
#pragma unroll
            for (int i = 0; i < 16; i++) {
                int idx = t + i * 256;
                int kk = idx >> 6, nn = idx & 63;
                long off = (long)(k0 + kk) * HID + n0 + nn;
                s[kk][nn] = isbf ? ((const uint16_t*)W)[off] : f2bf(((const float*)W)[off]);
            }
            __syncthreads();
#pragma unroll
            for (int i = 0; i < 16; i++) {
                int idx = t + i * 256;
                int nn = idx >> 6, kk = idx & 63;
                Wt[(long)(n0 + nn) * HID + k0 + kk] = s[kk][nn];
            }
        } else {
            int n0 = (bb - 488) * 64;
#pragma unroll
            for (int i = 0; i < 16; i++) {
                int idx = t + i * 256;
                int kk = idx >> 6, nn = idx & 63;
                uint16_t v = 0;
                if (kk < FEA) {
                    long off = (long)kk * HID + n0 + nn;
                    v = isbf ? ((const uint16_t*)a.w1)[off] : f2bf(((const float*)a.w1)[off]);
                }
                s[kk][nn] = v;
            }
            __syncthreads();
#pragma unroll
            for (int i = 0; i < 16; i++) {
                int idx = t + i * 256;
                int nn = idx >> 6, kk = idx & 63;
                a.w1t[(long)(n0 + nn) * 64 + kk] = s[kk][nn];
            }
        }
    } else {
        // ---- bucket-CSR scatter, NT stores ----
        int e0 = ((b - NB_CVT - NB_TR) * 256 + t) * 2;
        int E = a.E;
        if (e0 >= E) return;
        int i64 = flags[1];
        int r0, r1 = -1, c0, c1 = -1;
        if (i64) {
            const long long* pr = (const long long*)a.ei + e0;
            const long long* pc = (const long long*)a.ei + E + e0;
            r0 = (int)pr[0]; c0 = (int)pc[0];
            if (e0 + 1 < E) { r1 = (int)pr[1]; c1 = (int)pc[1]; }
        } else {
            const int* pr = (const int*)a.ei + e0;
            const int* pc = (const int*)a.ei + E + e0;
            r0 = pr[0]; c0 = pc[0];
            if (e0 + 1 < E) { r1 = pr[1]; c1 = pc[1]; }
        }
        float w0, w1 = 0.f;
        if (isbf) {
            uint32_t ww = ((const uint32_t*)a.ew)[e0 >> 1];
            w0 = bf2f((uint16_t)(ww & 0xffff));
            w1 = bf2f((uint16_t)(ww >> 16));
        } else {
            float2 f = ((const float2*)a.ew)[e0 >> 1];
            w0 = f.x; w1 = f.y;
        }
        int p0 = atomicAdd(&a.count[c0], 1);
        unsigned long long v0 = (unsigned long long)(uint32_t)r0 |
                                ((unsigned long long)__float_as_uint(w0) << 32);
        __builtin_nontemporal_store(v0, (unsigned long long*)&a.adj[((long)c0 << 6) + p0]);
        if (c1 >= 0) {
            int p1 = atomicAdd(&a.count[c1], 1);
            unsigned long long v1 = (unsigned long long)(uint32_t)r1 |
                                    ((unsigned long long)__float_as_uint(w1) << 32);
            __builtin_nontemporal_store(v1, (unsigned long long*)&a.adj[((long)c1 << 6) + p1]);
        }
    }
}

// dinv = 1/sqrt(1 + row-sum of raw ew) over bucket
__global__ void k_rowsum(const int* count, const uint2* adj, float* dinv, int n) {
    int i = blockIdx.x * blockDim.x + threadIdx.x;
    if (i >= n) return;
    int cnt = count[i];
    const uint2* row = adj + ((long)i << 6);
    double d = 1.0;
    for (int p = 0; p < cnt; p++) {
        uint2 v = nt_load_u2(&row[p]);
        d += (double)__uint_as_float(v.y);
    }
    dinv[i] = (float)(1.0 / sqrt(d));
}

// ---------------- layer-1 pre-aggregation on x64 [N][64] (round-7 form) --------
__global__ __launch_bounds__(256) void k_aggx(const uint16_t* __restrict__ x64,
                                              const float* __restrict__ dinv,
                                              const int* __restrict__ count,
                                              const uint2* __restrict__ adj,
                                              uint16_t* __restrict__ xa, int n) {
    __shared__ uint2 sadj[8][32];
    int hv = threadIdx.x >> 5;
    int l = threadIdx.x & 31;
    int node = blockIdx.x * 8 + hv;
    if (node >= n) return;
    const uint32_t* xu = (const uint32_t*)x64;
    float di = dinv[node];
    float c2 = di * di;
    uint32_t h = xu[(long)node * 32 + l];
    float a0 = c2 * bf2f((uint16_t)(h & 0xffff));
    float a1 = c2 * bf2f((uint16_t)(h >> 16));
    int cnt = count[node];
    const uint2* row = adj + ((long)node << 6);
    for (int base = 0; base < cnt; base += 32) {
        int m = cnt - base; if (m > 32) m = 32;
        if (l < m) {
            uint2 a = nt_load_u2(&row[base + l]);
            float w = __uint_as_float(a.y) * dinv[a.x] * di;
            uint2 p; p.x = a.x; p.y = __float_as_uint(w);
            sadj[hv][l] = p;
        }
        int t = 0;
        for (; t + 4 <= m; t += 4) {
            uint2 e0 = sadj[hv][t], e1 = sadj[hv][t + 1], e2 = sadj[hv][t + 2], e3 = sadj[hv][t + 3];
            uint32_t v0 = xu[(long)e0.x * 32 + l];
            uint32_t v1 = xu[(long)e1.x * 32 + l];
            uint32_t v2 = xu[(long)e2.x * 32 + l];
            uint32_t v3 = xu[(long)e3.x * 32 + l];
            float w0 = __uint_as_float(e0.y), w1 = __uint_as_float(e1.y);
            float w2 = __uint_as_float(e2.y), w3 = __uint_as_float(e3.y);
            a0 += w0 * bf2f((uint16_t)(v0 & 0xffff)); a1 += w0 * bf2f((uint16_t)(v0 >> 16));
            a0 += w1 * bf2f((uint16_t)(v1 & 0xffff)); a1 += w1 * bf2f((uint16_t)(v1 >> 16));
            a0 += w2 * bf2f((uint16_t)(v2 & 0xffff)); a1 += w2 * bf2f((uint16_t)(v2 >> 16));
            a0 += w3 * bf2f((uint16_t)(v3 & 0xffff)); a1 += w3 * bf2f((uint16_t)(v3 >> 16));
        }
        for (; t < m; t++) {
            uint2 e0 = sadj[hv][t];
            uint32_t v0 = xu[(long)e0.x * 32 + l];
            float w0 = __uint_as_float(e0.y);
            a0 += w0 * bf2f((uint16_t)(v0 & 0xffff));
            a1 += w0 * bf2f((uint16_t)(v0 >> 16));
        }
    }
    ((uint32_t*)xa)[(long)node * 32 + l] =
        (uint32_t)f2bf(a0) | ((uint32_t)f2bf(a1) << 16);
}

// ---------------- 256-col aggregation (round-7 form): half-wave/node, uint4 ------
__device__ __forceinline__ void fma8(float* acc, float w, uint4 v) {
    acc[0] += w * bf2f((uint16_t)(v.x & 0xffff));
    acc[1] += w * bf2f((uint16_t)(v.x >> 16));
    acc[2] += w * bf2f((uint16_t)(v.y & 0xffff));
    acc[3] += w * bf2f((uint16_t)(v.y >> 16));
    acc[4] += w * bf2f((uint16_t)(v.z & 0xffff));
    acc[5] += w * bf2f((uint16_t)(v.z >> 16));
    acc[6] += w * bf2f((uint16_t)(v.w & 0xffff));
    acc[7] += w * bf2f((uint16_t)(v.w >> 16));
}

__global__ __launch_bounds__(256) void k_aggb(const uint16_t* __restrict__ hw,
                                              const float* __restrict__ dinv,
                                              const int* __restrict__ count,
                                              const uint2* __restrict__ adj,
                                              const float* __restrict__ bias,
                                              uint16_t* __restrict__ out, int n) {
    __shared__ uint2 sadj[8][32];
    int hv = threadIdx.x >> 5;
    int l = threadIdx.x & 31;
    int node = blockIdx.x * 8 + hv;
    if (node >= n) return;
    const uint4* hw4 = (const uint4*)hw;
    float di = dinv[node];
    float c2 = di * di;
    uint4 h = hw4[(long)node * 32 + l];
    float acc[8];
    acc[0] = c2 * bf2f((uint16_t)(h.x & 0xffff));
    acc[1] = c2 * bf2f((uint16_t)(h.x >> 16));
    acc[2] = c2 * bf2f((uint16_t)(h.y & 0xffff));
    acc[3] = c2 * bf2f((uint16_t)(h.y >> 16));
    acc[4] = c2 * bf2f((uint16_t)(h.z & 0xffff));
    acc[5] = c2 * bf2f((uint16_t)(h.z >> 16));
    acc[6] = c2 * bf2f((uint16_t)(h.w & 0xffff));
    acc[7] = c2 * bf2f((uint16_t)(h.w >> 16));
    int cnt = count[node];
    const uint2* row = adj + ((long)node << 6);
    for (int base = 0; base < cnt; base += 32) {
        int m = cnt - base; if (m > 32) m = 32;
        if (l < m) {
            uint2 a = nt_load_u2(&row[base + l]);
            float w = __uint_as_float(a.y) * dinv[a.x] * di;
            uint2 p; p.x = a.x; p.y = __float_as_uint(w);
            sadj[hv][l] = p;
        }
        int t = 0;
        for (; t + 4 <= m; t += 4) {
            uint2 e0 = sadj[hv][t], e1 = sadj[hv][t + 1], e2 = sadj[hv][t + 2], e3 = sadj[hv][t + 3];
            uint4 v0 = hw4[(long)e0.x * 32 + l];
            uint4 v1 = hw4[(long)e1.x * 32 + l];
            uint4 v2 = hw4[(long)e2.x * 32 + l];
            uint4 v3 = hw4[(long)e3.x * 32 + l];
            fma8(acc, __uint_as_float(e0.y), v0);
            fma8(acc, __uint_as_float(e1.y), v1);
            fma8(acc, __uint_as_float(e2.y), v2);
            fma8(acc, __uint_as_float(e3.y), v3);
        }
        for (; t < m; t++) {
            uint2 e0 = sadj[hv][t];
            uint4 v0 = hw4[(long)e0.x * 32 + l];
            fma8(acc, __uint_as_float(e0.y), v0);
        }
    }
    float4 ba = ((const float4*)bias)[l * 2];
    float4 bb = ((const float4*)bias)[l * 2 + 1];
    acc[0] += ba.x; acc[1] += ba.y; acc[2] += ba.z; acc[3] += ba.w;
    acc[4] += bb.x; acc[5] += bb.y; acc[6] += bb.z; acc[7] += bb.w;
#pragma unroll
    for (int k = 0; k < 8; k++) acc[k] = acc[k] > 0.f ? acc[k] : NEG * acc[k];
    uint4 o;
    o.x = (uint32_t)f2bf(acc[0]) | ((uint32_t)f2bf(acc[1]) << 16);
    o.y = (uint32_t)f2bf(acc[2]) | ((uint32_t)f2bf(acc[3]) << 16);
    o.z = (uint32_t)f2bf(acc[4]) | ((uint32_t)f2bf(acc[5]) << 16);
    o.w = (uint32_t)f2bf(acc[6]) | ((uint32_t)f2bf(acc[7]) << 16);
    ((uint4*)out)[(long)node * 32 + l] = o;
}

// ---------------- bf16 MFMA GEMM (plain A) ----------------
__global__ __launch_bounds__(256) void k_mgemm(const uint16_t* __restrict__ A,
                                               const uint16_t* __restrict__ Bt,
                                               uint16_t* __restrict__ outb,
                                               const float* __restrict__ bias,
                                               int M, int K, int act) {
    __shared__ uint16_t As[128 * 40];
    __shared__ uint16_t Bs[128 * 40];
    int tid = threadIdx.x;
    int lane = tid & 63, wv = tid >> 6;
    int quad = lane >> 4, l15 = lane & 15;
    int row0 = blockIdx.y * 128, col0 = blockIdx.x * 128;
    int arow = (wv >> 1) * 64;
    int bcol = (wv & 1) * 64;

    f32x4 acc[4][4];
#pragma unroll
    for (int i = 0; i < 4; i++)
#pragma unroll
        for (int j = 0; j < 4; j++) acc[i][j] = (f32x4){0.f, 0.f, 0.f, 0.f};

    for (int kc = 0; kc < K; kc += 32) {
#pragma unroll
        for (int i = 0; i < 2; i++) {
            int idx = tid + i * 256;
            int r = idx >> 2, cq = idx & 3;
            uint4 va = *(const uint4*)(A + (long)(row0 + r) * K + kc + cq * 8);
            *(uint4*)(&As[r * 40 + cq * 8]) = va;
            uint4 vb = *(const uint4*)(Bt + (long)(col0 + r) * K + kc + cq * 8);
            *(uint4*)(&Bs[r * 40 + cq * 8]) = vb;
        }
        __syncthreads();
        bf16x8 af[4], bfr[4];
#pragma unroll
        for (int i = 0; i < 4; i++)
            af[i] = __builtin_bit_cast(bf16x8,
                *(const uint4*)(&As[(arow + i * 16 + l15) * 40 + quad * 8]));
#pragma unroll
        for (int j = 0; j < 4; j++)
            bfr[j] = __builtin_bit_cast(bf16x8,
                *(const uint4*)(&Bs[(bcol + j * 16 + l15) * 40 + quad * 8]));
#pragma unroll
        for (int i = 0; i < 4; i++)
#pragma unroll
            for (int j = 0; j < 4; j++)
                acc[i][j] = __builtin_amdgcn_mfma_f32_16x16x32_bf16(af[i], bfr[j], acc[i][j], 0, 0, 0);
        __syncthreads();
    }

#pragma unroll
    for (int i = 0; i < 4; i++)
#pragma unroll
        for (int j = 0; j < 4; j++) {
            int row = row0 + arow + i * 16 + quad * 4;
            int col = col0 + bcol + j * 16 + l15;
#pragma unroll
            for (int reg = 0; reg < 4; reg++) {
                float v = acc[i][j][reg];
                if (bias) v += bias[col];
                if (act) v = v > 0.f ? v : NEG * v;
                outb[(long)(row + reg) * HID + col] = f2bf(v);
            }
        }
}

// ---------------- bf16 MFMA GEMM, VIRTUAL flat A (mlp0), atomic epilogue ----------
__global__ __launch_bounds__(256) void k_mgemm_flat(const uint16_t* __restrict__ h2,
                                                    const uint16_t* __restrict__ x64,
                                                    const uint16_t* __restrict__ Bt,
                                                    float* __restrict__ z0acc,
                                                    int M) {
    __shared__ uint16_t As[128 * 40];
    __shared__ uint16_t Bs[128 * 40];
    int tid = threadIdx.x;
    int lane = tid & 63, wv = tid >> 6;
    int quad = lane >> 4, l15 = lane & 15;
    int row0 = blockIdx.y * 128, col0 = blockIdx.x * 128;
    int kbeg = blockIdx.z * KC0;
    int kend = kbeg + KC0; if (kend > FLATP2) kend = FLATP2;
    int arow = (wv >> 1) * 64;
    int bcol = (wv & 1) * 64;

    f32x4 acc[4][4];
#pragma unroll
    for (int i = 0; i < 4; i++)
#pragma unroll
        for (int j = 0; j < 4; j++) acc[i][j] = (f32x4){0.f, 0.f, 0.f, 0.f};

    for (int kc = kbeg; kc < kend; kc += 32) {
#pragma unroll
        for (int i = 0; i < 2; i++) {
            int idx = tid + i * 256;
            int r = idx >> 2, cq = idx & 3;
            int gk = kc + cq * 8;
            int m = gk / PERM2;
            int k2 = gk - m * PERM2;
            long node = (long)(row0 + r) * MACH + m;
            uint4 va = (k2 < HID)
                ? *(const uint4*)(h2 + node * HID + k2)
                : *(const uint4*)(x64 + node * 64 + (k2 - HID));
            *(uint4*)(&As[r * 40 + cq * 8]) = va;
            uint4 vb = *(const uint4*)(Bt + (long)(col0 + r) * FLATP2 + gk);
            *(uint4*)(&Bs[r * 40 + cq * 8]) = vb;
        }
        __syncthreads();
        bf16x8 af[4], bfr[4];
#pragma unroll
        for (int i = 0; i < 4; i++)
            af[i] = __builtin_bit_cast(bf16x8,
                *(const uint4*)(&As[(arow + i * 16 + l15) * 40 + quad * 8]));
#pragma unroll
        for (int j = 0; j < 4; j++)
            bfr[j] = __builtin_bit_cast(bf16x8,
                *(const uint4*)(&Bs[(bcol + j * 16 + l15) * 40 + quad * 8]));
#pragma unroll
        for (int i = 0; i < 4; i++)
#pragma unroll
            for (int j = 0; j < 4; j++)
                acc[i][j] = __builtin_amdgcn_mfma_f32_16x16x32_bf16(af[i], bfr[j], acc[i][j], 0, 0, 0);
        __syncthreads();
    }

#pragma unroll
    for (int i = 0; i < 4; i++)
#pragma unroll
        for (int j = 0; j < 4; j++) {
            int row = row0 + arow + i * 16 + quad * 4;
            int col = col0 + bcol + j * 16 + l15;
#pragma unroll
            for (int reg = 0; reg < 4; reg++)
                atomicAdd(&z0acc[(long)(row + reg) * HID + col], acc[i][j][reg]);
        }
}

// ---------------- fused tail: z0acc+bf0+lrelu -> mlp1 -> mlp2 -> out ------
__global__ __launch_bounds__(256) void k_tail(const float* __restrict__ z0acc,
                                              const float* __restrict__ bf0,
                                              const uint16_t* __restrict__ Wf1t,
                                              const float* __restrict__ bf1,
                                              const uint16_t* __restrict__ Wf2t,
                                              const float* __restrict__ bf2,
                                              const float* __restrict__ Wo,
                                              const float* __restrict__ bo,
                                              void* out, const int* flags) {
    __shared__ uint16_t z0s[16 * 256];
    __shared__ uint16_t z1s[16 * 256];
    __shared__ uint16_t z2s[16 * 256];
    __shared__ float hred[256];
    int tid = threadIdx.x;
    int lane = tid & 63, wv = tid >> 6;
    int quad = lane >> 4, l15 = lane & 15;
    int rows0 = blockIdx.x * 16;
    int nw = wv * 64;

    for (int i = tid; i < 16 * 256; i += 256) {
        int rr = i >> 8, cc = i & 255;
        float v = z0acc[(long)(rows0 + rr) * HID + cc] + bf0[cc];
        v = v > 0.f ? v : NEG * v;
        z0s[i] = f2bf(v);
    }
    __syncthreads();

    {
        f32x4 acc[4];
#pragma unroll
        for (int j = 0; j < 4; j++) acc[j] = (f32x4){0.f, 0.f, 0.f, 0.f};
        for (int kc = 0; kc < HID; kc += 32) {
            bf16x8 a = __builtin_bit_cast(bf16x8,
                *(const uint4*)(&z0s[l15 * 256 + kc + quad * 8]));
#pragma unroll
            for (int j = 0; j < 4; j++) {
                bf16x8 b = __builtin_bit_cast(bf16x8,
                    *(const uint4*)(Wf1t + (long)(nw + j * 16 + l15) * HID + kc + quad * 8));
                acc[j] = __builtin_amdgcn_mfma_f32_16x16x32_bf16(a, b, acc[j], 0, 0, 0);
            }
        }
#pragma unroll
        for (int j = 0; j < 4; j++) {
            int col = nw + j * 16 + l15;
            float bj = bf1[col];
#pragma unroll
            for (int reg = 0; reg < 4; reg++) {
                float v = acc[j][reg] + bj;
                v = v > 0.f ? v : NEG * v;
                z1s[(quad * 4 + reg) * 256 + col] = f2bf(v);
            }
        }
    }
    __syncthreads();

    {
        f32x4 acc[4];
#pragma unroll
        for (int j = 0; j < 4; j++) acc[j] = (f32x4){0.f, 0.f, 0.f, 0.f};
        for (int kc = 0; kc < HID; kc += 32) {
            bf16x8 a = __builtin_bit_cast(bf16x8,
                *(const uint4*)(&z1s[l15 * 256 + kc + quad * 8]));
#pragma unroll
            for (int j = 0; j < 4; j++) {
                bf16x8 b = __builtin_bit_cast(bf16x8,
                    *(const uint4*)(Wf2t + (long)(nw + j * 16 + l15) * HID + kc + quad * 8));
                acc[j] = __builtin_amdgcn_mfma_f32_16x16x32_bf16(a, b, acc[j], 0, 0, 0);
            }
        }
#pragma unroll
        for (int j = 0; j < 4; j++) {
            int col = nw + j * 16 + l15;
            float bj = bf2[col];
#pragma unroll
            for (int reg = 0; reg < 4; reg++) {
                float v = acc[j][reg] + bj;
                v = v > 0.f ? v : NEG * v;
                z2s[(quad * 4 + reg) * 256 + col] = f2bf(v);
            }
        }
    }
    __syncthreads();

    // output head: 256 threads — (r,o) pairs x 4 partial sums, LDS reduce
    {
        int r = tid >> 4, o = (tid >> 2) & 3, part = tid & 3;
        float acc = 0.f;
        int k0 = part * 64;
        for (int k = k0; k < k0 + 64; k++)
            acc += bf2f(z2s[r * 256 + k]) * Wo[k * 4 + o];
        hred[tid] = acc;
    }
    __syncthreads();
    if ((tid & 3) == 0) {
        int r = tid >> 4, o = (tid >> 2) & 3;
        float v = hred[tid] + hred[tid + 1] + hred[tid + 2] + hred[tid + 3] + bo[o];
        long idx = (long)(rows0 + r) * 4 + o;
        if (flags[0]) ((uint16_t*)out)[idx] = f2bf(v);
        else          ((float*)out)[idx] = v;
    }
}

// ---------------- host ----------------
extern "C" void kernel_launch(void* const* d_in, const int* in_sizes, int n_in,
                              void* d_out, int out_size, void* d_ws, size_t ws_size,
                              hipStream_t stream) {
    const int N  = in_sizes[0] / FEA;   // 45056
    const int E  = in_sizes[2];         // 720896
    const int Bn = N / MACH;            // 2048

    char* ws = (char*)d_ws;
    size_t off = 0;
    auto alloc = [&](size_t bytes) -> char* {
        char* p = ws + off;
        off = (off + bytes + 255) & ~(size_t)255;
        return p;
    };

    int*      flags  = (int*)     alloc(64);
    uint16_t* x64    = (uint16_t*)alloc((size_t)N * 64 * 2);
    uint16_t* xa     = (uint16_t*)alloc((size_t)N * 64 * 2);
    uint16_t* W1t    = (uint16_t*)alloc((size_t)HID * 64 * 2);
    uint16_t* W2t    = (uint16_t*)alloc((size_t)HID * HID * 2);
    uint16_t* Wf0t   = (uint16_t*)alloc((size_t)HID * FLATP2 * 2);
    uint16_t* Wf1t   = (uint16_t*)alloc((size_t)HID * HID * 2);
    uint16_t* Wf2t   = (uint16_t*)alloc((size_t)HID * HID * 2);
    float*    b1     = (float*)   alloc(HID * 4);
    float*    b2     = (float*)   alloc(HID * 4);
    float*    bf0    = (float*)   alloc(HID * 4);
    float*    bf1    = (float*)   alloc(HID * 4);
    float*    bf2    = (float*)   alloc(HID * 4);
    float*    Wo     = (float*)   alloc((size_t)HID * 4 * 4);
    float*    bo     = (float*)   alloc(4 * 4);
    int*      count  = (int*)     alloc((size_t)N * 4);
    uint2*    adj    = (uint2*)   alloc((size_t)N * BCAP * 8);   // 23 MB buckets
    float*    dinv   = (float*)   alloc((size_t)N * 4);
    uint16_t* P      = (uint16_t*)alloc((size_t)N * HID * 2);    // h1 / h2
    uint16_t* Q      = (uint16_t*)alloc((size_t)N * HID * 2);    // hw
    float*    z0acc  = (float*)   alloc((size_t)Bn * HID * 4);   // 2 MB fp32 accumulator
    (void)ws_size; (void)n_in; (void)out_size;

    // 1. detect + zero count + zero z0acc
    k_detect_init<<<(Bn * HID) / 256, 256, 0, stream>>>(
        (const uint32_t*)d_in[2], (const uint32_t*)d_in[1], flags, count, z0acc, N);

    // 2. mega-prep: conversions + weight transposes + edge scatter
    PrepAll pa{};
    pa.xsrc = d_in[0]; pa.x64 = x64;
    const void* s8[7] = { d_in[4], d_in[6], d_in[8], d_in[10], d_in[12], d_in[13], d_in[14] };
    float* d8[7] = { b1, b2, bf0, bf1, bf2, Wo, bo };
    long n8[7] = { HID, HID, HID, HID, HID, (long)HID * 4, 4 };
    pa.cnt8 = 7;
    pa.prefix[0] = 0;
    for (int t = 0; t < 7; t++) { pa.src8[t] = s8[t]; pa.dst8[t] = d8[t]; pa.prefix[t + 1] = pa.prefix[t] + n8[t]; }
    pa.prefix[8] = pa.prefix[7];
    pa.wf0 = d_in[7]; pa.wf0t = Wf0t;
    pa.src3[0] = d_in[5];  pa.dst3[0] = W2t;
    pa.src3[1] = d_in[9];  pa.dst3[1] = Wf1t;
    pa.src3[2] = d_in[11]; pa.dst3[2] = Wf2t;
    pa.w1 = d_in[3]; pa.w1t = W1t;
    pa.ei = d_in[1]; pa.ew = d_in[2]; pa.count = count; pa.adj = adj; pa.E = E;
    pa.n = N;
    int nb_sc = (E / 2 + 255) / 256;
    k_prep_all<<<NB_CVT + NB_TR + nb_sc, 256, 0, stream>>>(pa, flags);

    // 3. dinv from buckets
    k_rowsum<<<(N + 255) / 256, 256, 0, stream>>>(count, adj, dinv, N);

    // 4. GCN layer 1: xa = agg(x64) ; h1 = lrelu(xa @ W1t + b1)
    k_aggx<<<(N + 7) / 8, 256, 0, stream>>>(x64, dinv, count, adj, xa, N);
    k_mgemm<<<dim3(2, N / 128), 256, 0, stream>>>(xa, W1t, P, b1, N, 64, 1);

    // 5. GCN layer 2: hw = h1 @ W2t ; h2 = agg(hw) + b2, lrelu
    k_mgemm<<<dim3(2, N / 128), 256, 0, stream>>>(P, W2t, Q, nullptr, N, HID, 0);
    k_aggb<<<(N + 7) / 8, 256, 0, stream>>>(Q, dinv, count, adj, b2, P, N);

    // 6. mlp0: virtual-flat split-K (S=16, Kc=448), atomic accumulate into z0acc
    k_mgemm_flat<<<dim3(2, Bn / 128, S0), 256, 0, stream>>>(P, x64, Wf0t, z0acc, Bn);

    // 7. fused tail: bias/lrelu + mlp1 + mlp2 + out
    k_tail<<<Bn / 16, 256, 0, stream>>>(z0acc, bf0, Wf1t, bf1, Wf2t, bf2, Wo, bo,
                                        d_out, flags);
}